// Round 2
// baseline (45.852 us; speedup 1.0000x reference)
//
#include <hip/hip_runtime.h>

// TrajLoss: pos = cumsum(pred.reshape(B,T,2), axis=1);
// loss = sum((pos_x - true[:, :T])^2 + (pos_y - true[:, T:])^2)
// B=8192, L=2048, T=1024. traj_du_true (d_in[1]) is unused by the reference.
//
// Layout: one 64-lane wave per row. Lane reads float4 at k = j*64+lane
// (fully coalesced: wave covers 1 KiB contiguous per instruction).
// float4 k = (dx,dy) pairs t=2k and t=2k+1; truth is float2 at index k of
// tx/ty (also coalesced). Cumsum = 8 independent wave scans + serial carry.

constexpr int L_DIM = 2048;
constexpr int T_DIM = 1024;          // L/2
constexpr int ROWS_PER_BLOCK = 4;    // 4 waves x 64 lanes = 256 threads
constexpr int NJ = 8;                // float4 chunks per lane: 8*64*4 = 2048 floats

__global__ __launch_bounds__(256) void traj_loss_kernel(
    const float* __restrict__ pred,
    const float* __restrict__ pos_true,
    float* __restrict__ out,
    int B)
{
    const int wid  = threadIdx.x >> 6;
    const int lane = threadIdx.x & 63;
    const int row  = blockIdx.x * ROWS_PER_BLOCK + wid;

    float acc = 0.0f;

    if (row < B) {
        const float4* p4  = reinterpret_cast<const float4*>(pred + (size_t)row * L_DIM);
        const float2* tx2 = reinterpret_cast<const float2*>(pos_true + (size_t)row * L_DIM);
        const float2* ty2 = reinterpret_cast<const float2*>(pos_true + (size_t)row * L_DIM + T_DIM);

        // ---- coalesced loads: all independent, issue up front ----
        float4 v[NJ];
        float2 tx[NJ], ty[NJ];
#pragma unroll
        for (int j = 0; j < NJ; ++j) v[j]  = p4[j * 64 + lane];
#pragma unroll
        for (int j = 0; j < NJ; ++j) tx[j] = tx2[j * 64 + lane];
#pragma unroll
        for (int j = 0; j < NJ; ++j) ty[j] = ty2[j * 64 + lane];

        // ---- per-chunk pair sums; 8 independent wave inclusive scans ----
        float ix[NJ], iy[NJ];   // inclusive scan of per-lane pair sums
        float ox[NJ], oy[NJ];   // own pair sums (to derive exclusive)
#pragma unroll
        for (int j = 0; j < NJ; ++j) {
            ox[j] = v[j].x + v[j].z;
            oy[j] = v[j].y + v[j].w;
            ix[j] = ox[j];
            iy[j] = oy[j];
        }
#pragma unroll
        for (int d = 1; d < 64; d <<= 1) {
#pragma unroll
            for (int j = 0; j < NJ; ++j) {
                float ux = __shfl_up(ix[j], d);
                float uy = __shfl_up(iy[j], d);
                if (lane >= d) { ix[j] += ux; iy[j] += uy; }
            }
        }

        // ---- serial carry across j + squared error ----
        float cx = 0.0f, cy = 0.0f;
#pragma unroll
        for (int j = 0; j < NJ; ++j) {
            const float totx = __shfl(ix[j], 63);   // wave total of chunk j
            const float toty = __shfl(iy[j], 63);
            const float ex_base = cx + (ix[j] - ox[j]);   // exclusive prefix
            const float ey_base = cy + (iy[j] - oy[j]);

            const float px0 = ex_base + v[j].x;      // pos_x at t=2k
            const float px1 = px0     + v[j].z;      // pos_x at t=2k+1
            const float py0 = ey_base + v[j].y;
            const float py1 = py0     + v[j].w;

            float e;
            e = px0 - tx[j].x; acc += e * e;
            e = px1 - tx[j].y; acc += e * e;
            e = py0 - ty[j].x; acc += e * e;
            e = py1 - ty[j].y; acc += e * e;

            cx += totx;
            cy += toty;
        }
    }

    // ---- wave reduce ----
#pragma unroll
    for (int d = 32; d >= 1; d >>= 1) acc += __shfl_xor(acc, d);

    __shared__ float warp_sums[ROWS_PER_BLOCK];
    if (lane == 0) warp_sums[wid] = acc;
    __syncthreads();

    if (threadIdx.x == 0) {
        float s = 0.0f;
#pragma unroll
        for (int w = 0; w < ROWS_PER_BLOCK; ++w) s += warp_sums[w];
        atomicAdd(out, s);
    }
}

extern "C" void kernel_launch(void* const* d_in, const int* in_sizes, int n_in,
                              void* d_out, int out_size, void* d_ws, size_t ws_size,
                              hipStream_t stream) {
    const float* pred     = (const float*)d_in[0];  // traj_pred
    // d_in[1] = traj_du_true — unused by the reference
    const float* pos_true = (const float*)d_in[2];  // traj_pos_true
    float* out = (float*)d_out;

    const int B = in_sizes[0] / L_DIM;

    // d_out is poisoned (0xAA) by the harness — zero it every call
    // (memset node is graph-capturable).
    hipMemsetAsync(out, 0, sizeof(float), stream);

    const int grid = (B + ROWS_PER_BLOCK - 1) / ROWS_PER_BLOCK;
    traj_loss_kernel<<<grid, 256, 0, stream>>>(pred, pos_true, out, B);
}

// Round 3
// 43.298 us; speedup vs baseline: 1.0590x; 1.0590x over previous
//
#include <hip/hip_runtime.h>

// TrajLoss: pos = cumsum(pred.reshape(B,T,2), axis=1);
// loss = sum((pos_x - true[:, :T])^2 + (pos_y - true[:, T:])^2)
// B=8192, L=2048, T=1024. traj_du_true (d_in[1]) is unused by the reference.
//
// One 64-lane wave per row. Lane owns 64 B contiguous of pred per segment
// (4 float4 = 8 t-steps); row = 2 segments. All 16 float4 loads issued
// up-front (launch_bounds(256,4) gives VGPR headroom so the compiler keeps
// them in flight -> memory-level parallelism, the R1/R2 limiter).
// Cumsum: per-lane segment sums -> 2 wave scans -> serial segment carry.

constexpr int L_DIM = 2048;
constexpr int T_DIM = 1024;          // L/2
constexpr int ROWS_PER_BLOCK = 4;    // 4 waves x 64 lanes

__global__ __launch_bounds__(256, 4) void traj_loss_kernel(
    const float* __restrict__ pred,
    const float* __restrict__ pos_true,
    float* __restrict__ out,
    int B)
{
    const int wid  = threadIdx.x >> 6;
    const int lane = threadIdx.x & 63;
    const int row  = blockIdx.x * ROWS_PER_BLOCK + wid;

    float acc = 0.0f;

    if (row < B) {
        const float4* p4 = reinterpret_cast<const float4*>(pred + (size_t)row * L_DIM);          // 512 float4
        const float4* tX = reinterpret_cast<const float4*>(pos_true + (size_t)row * L_DIM);      // 256 float4
        const float4* tY = reinterpret_cast<const float4*>(pos_true + (size_t)row * L_DIM + T_DIM);

        // ---- issue ALL loads up front (16 x float4 per lane) ----
        float4 v[2][4];     // pred: segment s, lane base s*256 + lane*4
        float4 tx[2][2];    // truth x: s*128 + lane*2
        float4 ty[2][2];
#pragma unroll
        for (int s = 0; s < 2; ++s)
#pragma unroll
            for (int q = 0; q < 4; ++q)
                v[s][q] = p4[s * 256 + lane * 4 + q];
#pragma unroll
        for (int s = 0; s < 2; ++s)
#pragma unroll
            for (int r = 0; r < 2; ++r)
                tx[s][r] = tX[s * 128 + lane * 2 + r];
#pragma unroll
        for (int s = 0; s < 2; ++s)
#pragma unroll
            for (int r = 0; r < 2; ++r)
                ty[s][r] = tY[s * 128 + lane * 2 + r];

        // pin load ISSUE before compute (waitcnt still lands at first use)
        asm volatile("" ::: "memory");

        // ---- per-lane segment totals ----
        float sx[2], sy[2];
#pragma unroll
        for (int s = 0; s < 2; ++s) {
            sx[s] = (v[s][0].x + v[s][0].z) + (v[s][1].x + v[s][1].z)
                  + (v[s][2].x + v[s][2].z) + (v[s][3].x + v[s][3].z);
            sy[s] = (v[s][0].y + v[s][0].w) + (v[s][1].y + v[s][1].w)
                  + (v[s][2].y + v[s][2].w) + (v[s][3].y + v[s][3].w);
        }

        // ---- 2 segments x 2 axes wave inclusive scans (interleaved) ----
        float ix0 = sx[0], ix1 = sx[1], iy0 = sy[0], iy1 = sy[1];
#pragma unroll
        for (int d = 1; d < 64; d <<= 1) {
            float a = __shfl_up(ix0, d);
            float b = __shfl_up(ix1, d);
            float c = __shfl_up(iy0, d);
            float e = __shfl_up(iy1, d);
            if (lane >= d) { ix0 += a; ix1 += b; iy0 += c; iy1 += e; }
        }
        const float totx0 = __shfl(ix0, 63);   // segment-0 row total
        const float toty0 = __shfl(iy0, 63);

        // ---- error accumulation (all indices compile-time static) ----
#define SEG(s, bx, by)                                                  \
        { float rx = (bx), ry = (by), e;                                \
          rx += v[s][0].x; e = rx - tx[s][0].x; acc += e * e;           \
          ry += v[s][0].y; e = ry - ty[s][0].x; acc += e * e;           \
          rx += v[s][0].z; e = rx - tx[s][0].y; acc += e * e;           \
          ry += v[s][0].w; e = ry - ty[s][0].y; acc += e * e;           \
          rx += v[s][1].x; e = rx - tx[s][0].z; acc += e * e;           \
          ry += v[s][1].y; e = ry - ty[s][0].z; acc += e * e;           \
          rx += v[s][1].z; e = rx - tx[s][0].w; acc += e * e;           \
          ry += v[s][1].w; e = ry - ty[s][0].w; acc += e * e;           \
          rx += v[s][2].x; e = rx - tx[s][1].x; acc += e * e;           \
          ry += v[s][2].y; e = ry - ty[s][1].x; acc += e * e;           \
          rx += v[s][2].z; e = rx - tx[s][1].y; acc += e * e;           \
          ry += v[s][2].w; e = ry - ty[s][1].y; acc += e * e;           \
          rx += v[s][3].x; e = rx - tx[s][1].z; acc += e * e;           \
          ry += v[s][3].y; e = ry - ty[s][1].z; acc += e * e;           \
          rx += v[s][3].z; e = rx - tx[s][1].w; acc += e * e;           \
          ry += v[s][3].w; e = ry - ty[s][1].w; acc += e * e; }

        SEG(0, ix0 - sx[0],         iy0 - sy[0]);
        SEG(1, totx0 + ix1 - sx[1], toty0 + iy1 - sy[1]);
#undef SEG
    }

    // ---- wave reduce ----
#pragma unroll
    for (int d = 32; d >= 1; d >>= 1) acc += __shfl_xor(acc, d);

    __shared__ float warp_sums[ROWS_PER_BLOCK];
    if (lane == 0) warp_sums[wid] = acc;
    __syncthreads();

    if (threadIdx.x == 0) {
        float s = 0.0f;
#pragma unroll
        for (int w = 0; w < ROWS_PER_BLOCK; ++w) s += warp_sums[w];
        atomicAdd(out, s);
    }
}

extern "C" void kernel_launch(void* const* d_in, const int* in_sizes, int n_in,
                              void* d_out, int out_size, void* d_ws, size_t ws_size,
                              hipStream_t stream) {
    const float* pred     = (const float*)d_in[0];  // traj_pred
    // d_in[1] = traj_du_true — unused by the reference
    const float* pos_true = (const float*)d_in[2];  // traj_pos_true
    float* out = (float*)d_out;

    const int B = in_sizes[0] / L_DIM;

    // d_out is poisoned (0xAA) by the harness — zero it every call
    // (memset node is graph-capturable).
    hipMemsetAsync(out, 0, sizeof(float), stream);

    const int grid = (B + ROWS_PER_BLOCK - 1) / ROWS_PER_BLOCK;
    traj_loss_kernel<<<grid, 256, 0, stream>>>(pred, pos_true, out, B);
}

// Round 4
// 27.410 us; speedup vs baseline: 1.6728x; 1.5797x over previous
//
#include <hip/hip_runtime.h>

// TrajLoss: pos = cumsum(pred.reshape(B,T,2), axis=1);
// loss = sum((pos_x - true[:, :T])^2 + (pos_y - true[:, T:])^2)
// B=8192, L=2048, T=1024. traj_du_true (d_in[1]) is unused by the reference.
//
// R3 post-mortem: the 45 us floor was 2048 same-address atomicAdds
// serializing at the TCC atomic pipe (~22 ns each) — duration was invariant
// to load pattern AND to HBM traffic (L3-resident replays: 65 KB fetched,
// same 51 us). Fix: per-block partial -> d_ws (plain store, no contention),
// then a tiny second kernel reduces 2048 floats -> out. Zero atomics.

constexpr int L_DIM = 2048;
constexpr int T_DIM = 1024;          // L/2
constexpr int ROWS_PER_BLOCK = 4;    // 4 waves x 64 lanes

__global__ __launch_bounds__(256, 4) void traj_loss_kernel(
    const float* __restrict__ pred,
    const float* __restrict__ pos_true,
    float* __restrict__ partials,
    int B)
{
    const int wid  = threadIdx.x >> 6;
    const int lane = threadIdx.x & 63;
    const int row  = blockIdx.x * ROWS_PER_BLOCK + wid;

    float acc = 0.0f;

    if (row < B) {
        const float4* p4 = reinterpret_cast<const float4*>(pred + (size_t)row * L_DIM);          // 512 float4
        const float4* tX = reinterpret_cast<const float4*>(pos_true + (size_t)row * L_DIM);      // 256 float4
        const float4* tY = reinterpret_cast<const float4*>(pos_true + (size_t)row * L_DIM + T_DIM);

        // ---- loads: lane owns 64 B contiguous per segment, 2 segments ----
        float4 v[2][4];     // pred: segment s, lane base s*256 + lane*4
        float4 tx[2][2];    // truth x: s*128 + lane*2
        float4 ty[2][2];
#pragma unroll
        for (int s = 0; s < 2; ++s)
#pragma unroll
            for (int q = 0; q < 4; ++q)
                v[s][q] = p4[s * 256 + lane * 4 + q];
#pragma unroll
        for (int s = 0; s < 2; ++s)
#pragma unroll
            for (int r = 0; r < 2; ++r)
                tx[s][r] = tX[s * 128 + lane * 2 + r];
#pragma unroll
        for (int s = 0; s < 2; ++s)
#pragma unroll
            for (int r = 0; r < 2; ++r)
                ty[s][r] = tY[s * 128 + lane * 2 + r];

        // ---- per-lane segment totals ----
        float sx[2], sy[2];
#pragma unroll
        for (int s = 0; s < 2; ++s) {
            sx[s] = (v[s][0].x + v[s][0].z) + (v[s][1].x + v[s][1].z)
                  + (v[s][2].x + v[s][2].z) + (v[s][3].x + v[s][3].z);
            sy[s] = (v[s][0].y + v[s][0].w) + (v[s][1].y + v[s][1].w)
                  + (v[s][2].y + v[s][2].w) + (v[s][3].y + v[s][3].w);
        }

        // ---- 2 segments x 2 axes wave inclusive scans (interleaved) ----
        float ix0 = sx[0], ix1 = sx[1], iy0 = sy[0], iy1 = sy[1];
#pragma unroll
        for (int d = 1; d < 64; d <<= 1) {
            float a = __shfl_up(ix0, d);
            float b = __shfl_up(ix1, d);
            float c = __shfl_up(iy0, d);
            float e = __shfl_up(iy1, d);
            if (lane >= d) { ix0 += a; ix1 += b; iy0 += c; iy1 += e; }
        }
        const float totx0 = __shfl(ix0, 63);   // segment-0 row total
        const float toty0 = __shfl(iy0, 63);

        // ---- error accumulation (all indices compile-time static) ----
#define SEG(s, bx, by)                                                  \
        { float rx = (bx), ry = (by), e;                                \
          rx += v[s][0].x; e = rx - tx[s][0].x; acc += e * e;           \
          ry += v[s][0].y; e = ry - ty[s][0].x; acc += e * e;           \
          rx += v[s][0].z; e = rx - tx[s][0].y; acc += e * e;           \
          ry += v[s][0].w; e = ry - ty[s][0].y; acc += e * e;           \
          rx += v[s][1].x; e = rx - tx[s][0].z; acc += e * e;           \
          ry += v[s][1].y; e = ry - ty[s][0].z; acc += e * e;           \
          rx += v[s][1].z; e = rx - tx[s][0].w; acc += e * e;           \
          ry += v[s][1].w; e = ry - ty[s][0].w; acc += e * e;           \
          rx += v[s][2].x; e = rx - tx[s][1].x; acc += e * e;           \
          ry += v[s][2].y; e = ry - ty[s][1].x; acc += e * e;           \
          rx += v[s][2].z; e = rx - tx[s][1].y; acc += e * e;           \
          ry += v[s][2].w; e = ry - ty[s][1].y; acc += e * e;           \
          rx += v[s][3].x; e = rx - tx[s][1].z; acc += e * e;           \
          ry += v[s][3].y; e = ry - ty[s][1].z; acc += e * e;           \
          rx += v[s][3].z; e = rx - tx[s][1].w; acc += e * e;           \
          ry += v[s][3].w; e = ry - ty[s][1].w; acc += e * e; }

        SEG(0, ix0 - sx[0],         iy0 - sy[0]);
        SEG(1, totx0 + ix1 - sx[1], toty0 + iy1 - sy[1]);
#undef SEG
    }

    // ---- wave reduce ----
#pragma unroll
    for (int d = 32; d >= 1; d >>= 1) acc += __shfl_xor(acc, d);

    __shared__ float warp_sums[ROWS_PER_BLOCK];
    if (lane == 0) warp_sums[wid] = acc;
    __syncthreads();

    if (threadIdx.x == 0) {
        float s = 0.0f;
#pragma unroll
        for (int w = 0; w < ROWS_PER_BLOCK; ++w) s += warp_sums[w];
        partials[blockIdx.x] = s;   // plain store — no atomic contention
    }
}

__global__ __launch_bounds__(256) void reduce_kernel(
    const float* __restrict__ partials, float* __restrict__ out, int n)
{
    const int lane = threadIdx.x & 63;
    const int wid  = threadIdx.x >> 6;

    float s = 0.0f;
    for (int i = threadIdx.x; i < n; i += 256) s += partials[i];

#pragma unroll
    for (int d = 32; d >= 1; d >>= 1) s += __shfl_xor(s, d);

    __shared__ float ws[4];
    if (lane == 0) ws[wid] = s;
    __syncthreads();

    if (threadIdx.x == 0) out[0] = ws[0] + ws[1] + ws[2] + ws[3];
}

extern "C" void kernel_launch(void* const* d_in, const int* in_sizes, int n_in,
                              void* d_out, int out_size, void* d_ws, size_t ws_size,
                              hipStream_t stream) {
    const float* pred     = (const float*)d_in[0];  // traj_pred
    // d_in[1] = traj_du_true — unused by the reference
    const float* pos_true = (const float*)d_in[2];  // traj_pos_true
    float* out      = (float*)d_out;
    float* partials = (float*)d_ws;                 // grid floats, overwritten every call

    const int B = in_sizes[0] / L_DIM;
    const int grid = (B + ROWS_PER_BLOCK - 1) / ROWS_PER_BLOCK;   // 2048

    traj_loss_kernel<<<grid, 256, 0, stream>>>(pred, pos_true, partials, B);
    reduce_kernel<<<1, 256, 0, stream>>>(partials, out, grid);
}